// Round 12
// baseline (559.142 us; speedup 1.0000x reference)
//
#include <hip/hip_runtime.h>
#include <hip/hip_bf16.h>
#include <math.h>

#define Hdim 128
#define NCn  8000
#define NVn  16000
#define NE   60000
#define LITERS 10
#define NCB16 500    // c-blocks in node_fused (16 rows)
#define NVB16 1000   // v-blocks in node_fused
#define NCB32 250    // c-blocks in pq phase (32 rows)
#define NVB32 500
#define PREPB 1280   // prep_weights blocks inside prep_init (327680/256)
#define INITB 6000   // init blocks (4 nodes each)
#define HISTB 235    // hist blocks inside prep_init ((NE+255)/256)
#define FILLB 235    // fill blocks inside fill_pq

typedef __attribute__((ext_vector_type(8))) short s8v;   // 8 x bf16 (4 VGPRs)
typedef __attribute__((ext_vector_type(4))) float f4v;   // MFMA acc / float4

// fast transcendentals: v_exp_f32 / v_rcp_f32 based (tolerance is loose, bf16-level)
__device__ __forceinline__ float fexp(float x) { return __expf(x); }
__device__ __forceinline__ float elu_f(float x) { return x > 0.0f ? x : (fexp(x) - 1.0f); }
__device__ __forceinline__ float sigm_f(float x) {
    return __builtin_amdgcn_rcpf(1.0f + fexp(-x));
}
__device__ __forceinline__ float tanh_f(float x) {
    // 1 - 2/(exp(2x)+1); saturates correctly at +/-inf
    return 1.0f - 2.0f * __builtin_amdgcn_rcpf(1.0f + fexp(2.0f * x));
}
__device__ __forceinline__ unsigned short f2b(float x) {
    __hip_bfloat16 h = __float2bfloat16(x); return *(unsigned short*)&h;
}
__device__ __forceinline__ float b2f(unsigned short u) {
    __hip_bfloat16 h; *(unsigned short*)&h = u; return __bfloat162float(h);
}

// ---------------- merged prep: weight fragment cast + node init + edge histogram --------
// blocks [0,PREPB): prep_weights. [PREPB,PREPB+INITB): init (4 nodes/block).
// [PREPB+INITB, +HISTB): histogram of edge targets (cnts pre-zeroed by hipMemsetAsync).
__global__ void prep_init(const float* __restrict__ Wmsg_c, const float* __restrict__ Wmsg_v,
                          const float* __restrict__ Wns_c,  const float* __restrict__ Wns_v,
                          const float* __restrict__ Wg_c, const float* __restrict__ Ug_c,
                          const float* __restrict__ Wg_v, const float* __restrict__ Ug_v,
                          unsigned short* __restrict__ Fmsg_c, unsigned short* __restrict__ Fmsg_v,
                          unsigned short* __restrict__ Fns_c,  unsigned short* __restrict__ Fns_v,
                          unsigned short* __restrict__ Fcat_c, unsigned short* __restrict__ Fcat_v,
                          const float* __restrict__ cf, const float* __restrict__ vf,
                          const float* __restrict__ Wc, const float* __restrict__ bc,
                          const float* __restrict__ Wv, const float* __restrict__ bv,
                          const float* __restrict__ gc, const float* __restrict__ bcl,
                          const float* __restrict__ gv, const float* __restrict__ bvl,
                          float* __restrict__ hc, float* __restrict__ hv,
                          const int* __restrict__ tgt_c, const int* __restrict__ tgt_v,
                          int* __restrict__ cnt_c, int* __restrict__ cnt_v) {
    if (blockIdx.x >= PREPB + INITB) {
        int e = (blockIdx.x - PREPB - INITB) * 256 + threadIdx.x;
        if (e >= NE) return;
        atomicAdd(&cnt_c[tgt_c[e]], 1);
        atomicAdd(&cnt_v[tgt_v[e]], 1);
        return;
    }
    if (blockIdx.x < PREPB) {
        int idx = blockIdx.x * 256 + threadIdx.x;
        const int S1 = 4 * 32768;              // msg_c, msg_v, ns_c, ns_v  (F=8, KT=8, ld=128)
        const int S2 = S1 + 2 * 98304;         // cat_c, cat_v              (F=24, KT=8, ld=384)
        if (idx < S1) {
            int seg = idx >> 15, t = idx & 32767;
            const float* W = (seg == 0) ? Wmsg_c : (seg == 1) ? Wmsg_v : (seg == 2) ? Wns_c : Wns_v;
            unsigned short* outw = (seg == 0) ? Fmsg_c : (seg == 1) ? Fmsg_v : (seg == 2) ? Fns_c : Fns_v;
            int j = t & 7, lane = (t >> 3) & 63, t2 = t >> 9;
            int f = t2 & 7, kt = t2 >> 3;
            int n = f * 16 + (lane & 15), k = kt * 32 + (lane >> 4) * 8 + j;
            outw[t] = f2b(W[(size_t)k * 128 + n]);
        } else if (idx < S2) {
            int q = idx - S1;
            int seg = q / 98304, t = q - seg * 98304;
            const float* Wg = seg ? Wg_v : Wg_c;
            const float* Ug = seg ? Ug_v : Ug_c;
            unsigned short* outw = seg ? Fcat_v : Fcat_c;
            int j = t & 7, lane = (t >> 3) & 63, t2 = t >> 9;
            int f = t2 % 24, kt = t2 / 24;
            int n = f * 16 + (lane & 15), k = kt * 32 + (lane >> 4) * 8 + j;
            outw[t] = f2b((k < 128) ? Ug[(size_t)k * 384 + n] : Wg[(size_t)(k - 128) * 384 + n]);
        }
        return;
    }
    // ---- init: h = LN(0.1*f*W_in + b_in), f32 only ----
    int node = (blockIdx.x - PREPB) * 4 + (threadIdx.x >> 6);
    int lane = threadIdx.x & 63;
    const float *Win, *bin, *g, *bl;
    float f;
    float* outp;
    if (node < NCn) {
        f = cf[node]; Win = Wc; bin = bc; g = gc; bl = bcl;
        outp = hc + (size_t)node * Hdim;
    } else {
        int n2 = node - NCn;
        f = vf[n2]; Win = Wv; bin = bv; g = gv; bl = bvl;
        outp = hv + (size_t)n2 * Hdim;
    }
    f *= 0.1f;
    float x0 = f * Win[lane] + bin[lane];
    float x1 = f * Win[lane + 64] + bin[lane + 64];
    float s = x0 + x1;
    float sq = x0 * x0 + x1 * x1;
    #pragma unroll
    for (int off = 32; off > 0; off >>= 1) {
        s += __shfl_xor(s, off);
        sq += __shfl_xor(sq, off);
    }
    float m = s * (1.0f / 128.0f);
    float v = sq * (1.0f / 128.0f) - m * m;
    float inv = 1.0f / sqrtf(v + 1e-6f);
    outp[lane]      = g[lane]      * (x0 - m) * inv + bl[lane];
    outp[lane + 64] = g[lane + 64] * (x1 - m) * inv + bl[lane + 64];
}

// ---------------- CSR rowptr scan (shfl-based, 2 barriers) ----------------
__launch_bounds__(1024)
__global__ void scan2_kernel(const int* __restrict__ cnt_c, int* __restrict__ rp_c,
                             const int* __restrict__ cnt_v, int* __restrict__ rp_v) {
    const int* cnt = blockIdx.x ? cnt_v : cnt_c;
    int* rowptr = blockIdx.x ? rp_v : rp_c;
    const int n = blockIdx.x ? NVn : NCn;
    __shared__ int wsum[16];
    int t = threadIdx.x;
    int lane = t & 63, wid = t >> 6;
    int chunk = (n + 1023) >> 10;
    int base = t * chunk;
    int s = 0;
    for (int i = 0; i < chunk; i++) { int idx = base + i; if (idx < n) s += cnt[idx]; }
    // wave-level inclusive scan
    int sc = s;
    #pragma unroll
    for (int off = 1; off < 64; off <<= 1) {
        int u = __shfl_up(sc, off);
        if (lane >= off) sc += u;
    }
    if (lane == 63) wsum[wid] = sc;
    __syncthreads();
    if (wid == 0 && lane < 16) {
        int w = wsum[lane];
        int wscan = w;
        #pragma unroll
        for (int off = 1; off < 16; off <<= 1) {
            int u = __shfl_up(wscan, off);
            if (lane >= off) wscan += u;
        }
        wsum[lane] = wscan - w;   // exclusive wave prefix
    }
    __syncthreads();
    int run = wsum[wid] + sc - s;  // exclusive prefix for this thread
    for (int i = 0; i < chunk; i++) {
        int idx = base + i;
        if (idx < n) { rowptr[idx] = run; run += cnt[idx]; }
    }
    if (t == 1023) rowptr[n] = wsum[15] + sc;   // grand total (t=1023 is lane63 of wave15)
}

// ---------------- merged: CSR fill + P/Q init (independent work) ----------------
__launch_bounds__(256)
__global__ void fill_pq(const int* __restrict__ tgt_c, const int* __restrict__ tgt_v,
                        const int* __restrict__ src_c, const int* __restrict__ src_v,
                        const int* __restrict__ rp_c, const int* __restrict__ rp_v,
                        int* __restrict__ fill_c, int* __restrict__ fill_v,
                        int* __restrict__ srcs_c, int* __restrict__ srcs_v,
                        const float* __restrict__ hc, const float* __restrict__ hv,
                        const unsigned short* __restrict__ Fmsg_c, const unsigned short* __restrict__ Fmsg_v,
                        const float* __restrict__ bmsg_c, const float* __restrict__ bmsg_v,
                        unsigned short* __restrict__ Pv_w, unsigned short* __restrict__ Qc_w,
                        unsigned short* __restrict__ Pc_w, unsigned short* __restrict__ Qv_w) {
    if (blockIdx.x < FILLB) {
        int e = blockIdx.x * 256 + threadIdx.x;
        if (e >= NE) return;
        int tc = tgt_c[e];
        srcs_c[rp_c[tc] + atomicAdd(&fill_c[tc], 1)] = src_c[e];
        int tv = tgt_v[e];
        srcs_v[rp_v[tv] + atomicAdd(&fill_v[tv], 1)] = src_v[e];
        return;
    }
    __shared__ unsigned short sA[32 * 136];
    const int bid = blockIdx.x - FILLB;
    const int isV = (bid >= NCB32) ? 1 : 0;
    const int blockM = (isV ? (bid - NCB32) : bid) * 32;
    const float* h = isV ? hv : hc;
    const unsigned short* FP = isV ? Fmsg_c : Fmsg_v;   // P uses the OTHER direction's top half
    const unsigned short* FQ = isV ? Fmsg_v : Fmsg_c;   // Q uses own direction's bottom half
    const float* bq = isV ? bmsg_v : bmsg_c;
    unsigned short* Pw = isV ? Pv_w : Pc_w;
    unsigned short* Qw = isV ? Qv_w : Qc_w;

    const int tid = threadIdx.x;
    const int lane = tid & 63, wave = tid >> 6;
    const int quad = lane >> 4, l16 = lane & 15;
    {
        int rr = tid >> 3, cc = tid & 7;   // 32 rows, 8 threads/row, 16 elems each
        const float* hrow = &h[(size_t)(blockM + rr) * Hdim + cc * 16];
        f4v x0 = *(const f4v*)hrow;
        f4v x1 = *(const f4v*)(hrow + 4);
        f4v x2 = *(const f4v*)(hrow + 8);
        f4v x3 = *(const f4v*)(hrow + 12);
        s8v w0, w1;
        #pragma unroll
        for (int i = 0; i < 4; i++) {
            w0[i] = (short)f2b(x0[i]); w0[i + 4] = (short)f2b(x1[i]);
            w1[i] = (short)f2b(x2[i]); w1[i + 4] = (short)f2b(x3[i]);
        }
        *(s8v*)&sA[rr * 136 + cc * 16]     = w0;
        *(s8v*)&sA[rr * 136 + cc * 16 + 8] = w1;
    }
    __syncthreads();

    f4v accP[2][2], accQ[2][2];   // [mt][u]
    #pragma unroll
    for (int mt = 0; mt < 2; mt++)
        #pragma unroll
        for (int u = 0; u < 2; u++) { accP[mt][u] = (f4v){0.f,0.f,0.f,0.f}; accQ[mt][u] = (f4v){0.f,0.f,0.f,0.f}; }

    #pragma unroll
    for (int kt = 0; kt < 4; kt++) {
        s8v a0 = *(const s8v*)&sA[l16 * 136 + kt * 32 + quad * 8];
        s8v a1 = *(const s8v*)&sA[(16 + l16) * 136 + kt * 32 + quad * 8];
        #pragma unroll
        for (int u = 0; u < 2; u++) {
            int ct = wave * 2 + u;
            s8v bp = *(const s8v*)&FP[((size_t)(kt * 8 + ct) * 64 + lane) * 8];
            s8v bqv = *(const s8v*)&FQ[((size_t)((kt + 4) * 8 + ct) * 64 + lane) * 8];
            accP[0][u] = __builtin_amdgcn_mfma_f32_16x16x32_bf16(a0, bp, accP[0][u], 0, 0, 0);
            accP[1][u] = __builtin_amdgcn_mfma_f32_16x16x32_bf16(a1, bp, accP[1][u], 0, 0, 0);
            accQ[0][u] = __builtin_amdgcn_mfma_f32_16x16x32_bf16(a0, bqv, accQ[0][u], 0, 0, 0);
            accQ[1][u] = __builtin_amdgcn_mfma_f32_16x16x32_bf16(a1, bqv, accQ[1][u], 0, 0, 0);
        }
    }
    #pragma unroll
    for (int u = 0; u < 2; u++) {
        int col = (wave * 2 + u) * 16 + l16;
        float qbias = bq[col];
        #pragma unroll
        for (int mt = 0; mt < 2; mt++)
            #pragma unroll
            for (int reg = 0; reg < 4; reg++) {
                int row = blockM + mt * 16 + quad * 4 + reg;
                Pw[(size_t)row * Hdim + col] = f2b(accP[mt][u][reg]);
                Qw[(size_t)row * Hdim + col] = f2b(accQ[mt][u][reg] + qbias);
            }
    }
}

// ---------------- fused per-iteration node kernel (16-row blocks) ----------------
// __launch_bounds__(256, 6): cap VGPR at 85 so 6 blocks/CU fit -> all 1500 blocks of the
// grid resident in ONE cohort (was 108 VGPR -> 4 blocks/CU -> 1024+476 two-cohort drain).
// stage h(f32->bf16, f32 copy to padded LDS) FUSED with gather (8/4/2/1-deep batched) ->
// bar -> phase A (upd -> sU, fresh region) -> bar -> phase B (gates, split sH1(h@Ug)/
// sH2(upd@Wg)) + epilogue (hold from LDS) -> [last: fused final dot] -> bar -> new-h
// write -> bar -> phase C (next P/Q). Last iteration (vOnly): v-blocks only, no h write.
// skip8: penultimate iteration — c-tiles skip hc/Qc writes, v-tiles skip Pv write.
__launch_bounds__(256, 6)
__global__ void node_fused(float* __restrict__ hc, float* __restrict__ hv,
                           const int* __restrict__ rp_c, const int* __restrict__ rp_v,
                           const int* __restrict__ srcs_c, const int* __restrict__ srcs_v,
                           const unsigned short* __restrict__ Pv_r, const unsigned short* __restrict__ Qc_r,
                           const unsigned short* __restrict__ Pc_r, const unsigned short* __restrict__ Qv_r,
                           unsigned short* __restrict__ Pv_w, unsigned short* __restrict__ Qc_w,
                           unsigned short* __restrict__ Pc_w, unsigned short* __restrict__ Qv_w,
                           const unsigned short* __restrict__ Fns_c, const float* __restrict__ bns_c,
                           const unsigned short* __restrict__ Fns_v, const float* __restrict__ bns_v,
                           const unsigned short* __restrict__ Fcat_c, const unsigned short* __restrict__ Fcat_v,
                           const float* __restrict__ bg_c, const float* __restrict__ bg_v,
                           const unsigned short* __restrict__ Fmsg_c, const unsigned short* __restrict__ Fmsg_v,
                           const float* __restrict__ bmsg_c, const float* __restrict__ bmsg_v,
                           const float* __restrict__ Wf, const float* __restrict__ bf,
                           float* __restrict__ out, int do_pq, int vOnly, int skip8) {
    __shared__ unsigned short sA[16 * 264];   // [16 rows][256 k] stride 264 (8448 B)
    __shared__ unsigned short sU[16 * 136];   // upd rows, bf16 (4352 B)
    __shared__ float sHf[16 * 132];           // f32 copy of old h, stride 132 (8448 B)
    __shared__ float sRed[64];                // final-output reduce
    const int bid = blockIdx.x;
    const int isV = vOnly ? 1 : ((bid >= NCB16) ? 1 : 0);
    const int blockM = (vOnly ? bid : (isV ? (bid - NCB16) : bid)) * 16;
    float* h = isV ? hv : hc;
    const int* rp = isV ? rp_v : rp_c;
    const int* srcs = isV ? srcs_v : srcs_c;
    const unsigned short* Pr = isV ? Pc_r : Pv_r;   // messages into v come from c sources, vice versa
    const unsigned short* Qr = isV ? Qv_r : Qc_r;
    const unsigned short* Fns = isV ? Fns_v : Fns_c;
    const float* bns = isV ? bns_v : bns_c;
    const unsigned short* Fcat = isV ? Fcat_v : Fcat_c;
    const float* bg = isV ? bg_v : bg_c;
    const unsigned short* FP = isV ? Fmsg_c : Fmsg_v;
    const unsigned short* FQ = isV ? Fmsg_v : Fmsg_c;
    const float* bq = isV ? bmsg_v : bmsg_c;
    unsigned short* Pw = isV ? Pv_w : Pc_w;
    unsigned short* Qw = isV ? Qv_w : Qc_w;
    const int wrH = do_pq && !(skip8 && !isV);   // skip hc write on penultimate iter
    const int wrP = !(skip8 && isV);             // skip Pv write on penultimate iter
    const int wrQ = !(skip8 && !isV);            // skip Qc write on penultimate iter

    const int tid = threadIdx.x;
    const int lane = tid & 63, wave = tid >> 6;
    const int quad = lane >> 4, l16 = lane & 15;
    const int r = tid >> 4, ch = tid & 15;    // 16 rows x 16 col-slices of 8
    const int node = blockM + r;

    // ---- fused stage + gather (no barrier in between: gather uses only reg/global) ----
    {
        // independent loads first: Q row-slice, h row-slice, row extent
        s8v q8 = *(const s8v*)&Qr[(size_t)node * Hdim + ch * 8];
        const float* hrow = &h[(size_t)node * Hdim + ch * 8];
        f4v h0 = *(const f4v*)hrow;
        f4v h1 = *(const f4v*)(hrow + 4);
        int j = rp[node];
        const int e0 = rp[node + 1];

        // park h: bf16 into sA, f32 into padded sHf (for GRU hold)
        s8v hw;
        #pragma unroll
        for (int i = 0; i < 4; i++) { hw[i] = (short)f2b(h0[i]); hw[i + 4] = (short)f2b(h1[i]); }
        *(s8v*)&sA[r * 264 + ch * 8] = hw;
        *(f4v*)&sHf[r * 132 + ch * 8]     = h0;
        *(f4v*)&sHf[r * 132 + ch * 8 + 4] = h1;

        float qf[8], acc[8];
        #pragma unroll
        for (int i = 0; i < 8; i++) { qf[i] = b2f((unsigned short)q8[i]); acc[i] = 0.0f; }

        // 8-deep batch (covers most c-rows in one latency epoch)
        for (; j + 8 <= e0; j += 8) {
            s8v p[8];
            #pragma unroll
            for (int b = 0; b < 8; b++)
                p[b] = *(const s8v*)&Pr[(size_t)srcs[j + b] * Hdim + ch * 8];
            #pragma unroll
            for (int b = 0; b < 8; b++)
                #pragma unroll
                for (int i = 0; i < 8; i++) acc[i] += elu_f(b2f((unsigned short)p[b][i]) + qf[i]);
        }
        if (j + 4 <= e0) {
            s8v p[4];
            #pragma unroll
            for (int b = 0; b < 4; b++)
                p[b] = *(const s8v*)&Pr[(size_t)srcs[j + b] * Hdim + ch * 8];
            #pragma unroll
            for (int b = 0; b < 4; b++)
                #pragma unroll
                for (int i = 0; i < 8; i++) acc[i] += elu_f(b2f((unsigned short)p[b][i]) + qf[i]);
            j += 4;
        }
        if (j + 2 <= e0) {
            s8v p0 = *(const s8v*)&Pr[(size_t)srcs[j] * Hdim + ch * 8];
            s8v p1 = *(const s8v*)&Pr[(size_t)srcs[j + 1] * Hdim + ch * 8];
            #pragma unroll
            for (int i = 0; i < 8; i++) acc[i] += elu_f(b2f((unsigned short)p0[i]) + qf[i]);
            #pragma unroll
            for (int i = 0; i < 8; i++) acc[i] += elu_f(b2f((unsigned short)p1[i]) + qf[i]);
            j += 2;
        }
        if (j < e0) {
            s8v p0 = *(const s8v*)&Pr[(size_t)srcs[j] * Hdim + ch * 8];
            #pragma unroll
            for (int i = 0; i < 8; i++) acc[i] += elu_f(b2f((unsigned short)p0[i]) + qf[i]);
        }
        s8v w;
        #pragma unroll
        for (int i = 0; i < 8; i++) w[i] = (short)f2b(acc[i]);
        *(s8v*)&sA[r * 264 + 128 + ch * 8] = w;
    }
    __syncthreads();   // bar1

    // ---- phase A: upd = ELU([h|agg] @ Wns + bns) -> write to fresh sU (no pre-barrier) ----
    f4v accA[2];
    accA[0] = (f4v){0.f,0.f,0.f,0.f};
    accA[1] = (f4v){0.f,0.f,0.f,0.f};
    #pragma unroll
    for (int kt = 0; kt < 8; kt++) {
        s8v a = *(const s8v*)&sA[l16 * 264 + kt * 32 + quad * 8];
        #pragma unroll
        for (int u = 0; u < 2; u++) {
            s8v b = *(const s8v*)&Fns[((size_t)(kt * 8 + wave * 2 + u) * 64 + lane) * 8];
            accA[u] = __builtin_amdgcn_mfma_f32_16x16x32_bf16(a, b, accA[u], 0, 0, 0);
        }
    }
    #pragma unroll
    for (int u = 0; u < 2; u++) {
        int col = (wave * 2 + u) * 16 + l16;
        float bb = bns[col];
        #pragma unroll
        for (int reg = 0; reg < 4; reg++)
            sU[(quad * 4 + reg) * 136 + col] = f2b(elu_f(accA[u][reg] + bb));
    }
    __syncthreads();   // bar2: sU complete

    // ---- phase B: GRU gates; sH1 = h@Ug_h (kt<4), sH2 = upd@Wg_h (kt>=4) ----
    float hnv[2][4];
    #pragma unroll
    for (int u = 0; u < 2; u++) {
        const int j = wave * 2 + u;
        f4v sZ = (f4v){0.f,0.f,0.f,0.f};
        f4v sR = (f4v){0.f,0.f,0.f,0.f};
        f4v sH1 = (f4v){0.f,0.f,0.f,0.f};
        f4v sH2 = (f4v){0.f,0.f,0.f,0.f};
        #pragma unroll
        for (int kt = 0; kt < 8; kt++) {
            s8v a = (kt < 4)
                ? *(const s8v*)&sA[l16 * 264 + kt * 32 + quad * 8]
                : *(const s8v*)&sU[l16 * 136 + (kt - 4) * 32 + quad * 8];
            s8v bz = *(const s8v*)&Fcat[((size_t)(kt * 24 + j) * 64 + lane) * 8];
            s8v br = *(const s8v*)&Fcat[((size_t)(kt * 24 + 8 + j) * 64 + lane) * 8];
            s8v bh = *(const s8v*)&Fcat[((size_t)(kt * 24 + 16 + j) * 64 + lane) * 8];
            sZ = __builtin_amdgcn_mfma_f32_16x16x32_bf16(a, bz, sZ, 0, 0, 0);
            sR = __builtin_amdgcn_mfma_f32_16x16x32_bf16(a, br, sR, 0, 0, 0);
            if (kt < 4)
                sH1 = __builtin_amdgcn_mfma_f32_16x16x32_bf16(a, bh, sH1, 0, 0, 0);
            else
                sH2 = __builtin_amdgcn_mfma_f32_16x16x32_bf16(a, bh, sH2, 0, 0, 0);
        }
        const int t = j * 16 + l16;
        float bz2 = bg[t]       + bg[384 + t];
        float br2 = bg[128 + t] + bg[512 + t];
        float b0h = bg[256 + t];
        float b1h = bg[640 + t];
        #pragma unroll
        for (int reg = 0; reg < 4; reg++) {
            int rloc = quad * 4 + reg;
            float z = sigm_f(sZ[reg] + bz2);
            float rr = sigm_f(sR[reg] + br2);
            float hh = tanh_f((sH2[reg] + b0h) + rr * (sH1[reg] + b1h));
            float hold = sHf[rloc * 132 + t];
            float hn = z * hold + (1.0f - z) * hh;
            if (wrH) h[(size_t)(blockM + rloc) * Hdim + t] = hn;
            hnv[u][reg] = hn;
        }
    }

    if (!do_pq) {
        // ---- last iteration: fused final output out[i] = dot(hv[i], Wf) + bf ----
        float wf0 = Wf[(wave * 2 + 0) * 16 + l16];
        float wf1 = Wf[(wave * 2 + 1) * 16 + l16];
        float part[4];
        #pragma unroll
        for (int reg = 0; reg < 4; reg++)
            part[reg] = hnv[0][reg] * wf0 + hnv[1][reg] * wf1;
        #pragma unroll
        for (int off = 1; off < 16; off <<= 1) {
            #pragma unroll
            for (int reg = 0; reg < 4; reg++)
                part[reg] += __shfl_xor(part[reg], off);
        }
        if (l16 == 0) {
            #pragma unroll
            for (int reg = 0; reg < 4; reg++)
                sRed[wave * 16 + quad * 4 + reg] = part[reg];
        }
        __syncthreads();
        if (tid < 16)
            out[blockM + tid] = sRed[tid] + sRed[16 + tid] + sRed[32 + tid] + sRed[48 + tid] + bf[0];
        return;
    }

    __syncthreads();   // bar3: everyone done reading old h in sA[:,0:128)
    #pragma unroll
    for (int u = 0; u < 2; u++) {
        int col = (wave * 2 + u) * 16 + l16;
        #pragma unroll
        for (int reg = 0; reg < 4; reg++)
            sA[(quad * 4 + reg) * 264 + col] = f2b(hnv[u][reg]);
    }
    __syncthreads();   // bar4

    // ---- phase C: next-iteration P/Q from new h (K=128), bf16 out ----
    f4v accP[2], accQ[2];
    accP[0] = (f4v){0.f,0.f,0.f,0.f}; accP[1] = (f4v){0.f,0.f,0.f,0.f};
    accQ[0] = (f4v){0.f,0.f,0.f,0.f}; accQ[1] = (f4v){0.f,0.f,0.f,0.f};
    #pragma unroll
    for (int kt = 0; kt < 4; kt++) {
        s8v a = *(const s8v*)&sA[l16 * 264 + kt * 32 + quad * 8];
        #pragma unroll
        for (int u = 0; u < 2; u++) {
            int ct = wave * 2 + u;
            s8v bp = *(const s8v*)&FP[((size_t)(kt * 8 + ct) * 64 + lane) * 8];
            s8v bqv = *(const s8v*)&FQ[((size_t)((kt + 4) * 8 + ct) * 64 + lane) * 8];
            accP[u] = __builtin_amdgcn_mfma_f32_16x16x32_bf16(a, bp, accP[u], 0, 0, 0);
            accQ[u] = __builtin_amdgcn_mfma_f32_16x16x32_bf16(a, bqv, accQ[u], 0, 0, 0);
        }
    }
    #pragma unroll
    for (int u = 0; u < 2; u++) {
        int col = (wave * 2 + u) * 16 + l16;
        float qbias = bq[col];
        #pragma unroll
        for (int reg = 0; reg < 4; reg++) {
            int row = blockM + quad * 4 + reg;
            if (wrP) Pw[(size_t)row * Hdim + col] = f2b(accP[u][reg]);
            if (wrQ) Qw[(size_t)row * Hdim + col] = f2b(accQ[u][reg] + qbias);
        }
    }
}

extern "C" void kernel_launch(void* const* d_in, const int* in_sizes, int n_in,
                              void* d_out, int out_size, void* d_ws, size_t ws_size,
                              hipStream_t stream) {
    const float* cf      = (const float*)d_in[0];
    const float* vf      = (const float*)d_in[1];
    const int*   c2v_src = (const int*)d_in[2];
    const int*   c2v_tgt = (const int*)d_in[3];
    const int*   v2c_src = (const int*)d_in[4];
    const int*   v2c_tgt = (const int*)d_in[5];
    const float* Wc_in   = (const float*)d_in[6];
    const float* bc_in   = (const float*)d_in[7];
    const float* Wv_in   = (const float*)d_in[8];
    const float* bv_in   = (const float*)d_in[9];
    const float* gc_ln   = (const float*)d_in[10];
    const float* bc_ln   = (const float*)d_in[11];
    const float* gv_ln   = (const float*)d_in[12];
    const float* bv_ln   = (const float*)d_in[13];
    const float* Wmsg_c  = (const float*)d_in[14];
    const float* bmsg_c  = (const float*)d_in[15];
    const float* Wmsg_v  = (const float*)d_in[16];
    const float* bmsg_v  = (const float*)d_in[17];
    const float* Wns_c   = (const float*)d_in[18];
    const float* bns_c   = (const float*)d_in[19];
    const float* Wns_v   = (const float*)d_in[20];
    const float* bns_v   = (const float*)d_in[21];
    const float* Wg_c    = (const float*)d_in[22];
    const float* Ug_c    = (const float*)d_in[23];
    const float* bg_c    = (const float*)d_in[24];
    const float* Wg_v    = (const float*)d_in[25];
    const float* Ug_v    = (const float*)d_in[26];
    const float* bg_v    = (const float*)d_in[27];
    const float* Wf      = (const float*)d_in[28];
    const float* bf      = (const float*)d_in[29];
    float* out = (float*)d_out;

    // ---- workspace carve (256B-aligned) ----
    char* p = (char*)d_ws;
    #define CARVE(name, type, count) type* name = (type*)p; p += (((size_t)(count) * sizeof(type)) + 255) & ~(size_t)255;
    CARVE(hc,     float, NCn * Hdim)
    CARVE(hv,     float, NVn * Hdim)
    CARVE(Pv0,    unsigned short, NVn * Hdim)
    CARVE(Qc0,    unsigned short, NCn * Hdim)
    CARVE(Pc0,    unsigned short, NCn * Hdim)
    CARVE(Qv0,    unsigned short, NVn * Hdim)
    CARVE(Pv1,    unsigned short, NVn * Hdim)
    CARVE(Qc1,    unsigned short, NCn * Hdim)
    CARVE(Pc1,    unsigned short, NCn * Hdim)
    CARVE(Qv1,    unsigned short, NVn * Hdim)
    CARVE(Fmsg_c, unsigned short, 32768)
    CARVE(Fmsg_v, unsigned short, 32768)
    CARVE(Fns_c,  unsigned short, 32768)
    CARVE(Fns_v,  unsigned short, 32768)
    CARVE(Fcat_c, unsigned short, 98304)
    CARVE(Fcat_v, unsigned short, 98304)
    CARVE(rp_c,  int, NCn + 8)
    CARVE(rp_v,  int, NVn + 8)
    CARVE(srcs_c, int, NE)
    CARVE(srcs_v, int, NE)
    CARVE(cnts,  int, 48000)
    #undef CARVE
    int* cnt_c  = cnts;
    int* cnt_v  = cnts + NCn;
    int* fill_c = cnts + NCn + NVn;
    int* fill_v = cnts + 2 * NCn + NVn;

    // ---- once-per-call prep (memset + 3 dispatches) ----
    hipMemsetAsync(cnts, 0, 48000 * sizeof(int), stream);
    prep_init<<<PREPB + INITB + HISTB, 256, 0, stream>>>(
        Wmsg_c, Wmsg_v, Wns_c, Wns_v, Wg_c, Ug_c, Wg_v, Ug_v,
        Fmsg_c, Fmsg_v, Fns_c, Fns_v, Fcat_c, Fcat_v,
        cf, vf, Wc_in, bc_in, Wv_in, bv_in, gc_ln, bc_ln, gv_ln, bv_ln, hc, hv,
        v2c_tgt, c2v_tgt, cnt_c, cnt_v);
    scan2_kernel<<<2, 1024, 0, stream>>>(cnt_c, rp_c, cnt_v, rp_v);
    fill_pq<<<FILLB + NCB32 + NVB32, 256, 0, stream>>>(
        v2c_tgt, c2v_tgt, v2c_src, c2v_src, rp_c, rp_v, fill_c, fill_v, srcs_c, srcs_v,
        hc, hv, Fmsg_c, Fmsg_v, bmsg_c, bmsg_v, Pv0, Qc0, Pc0, Qv0);

    unsigned short* Pv_[2] = {Pv0, Pv1};
    unsigned short* Qc_[2] = {Qc0, Qc1};
    unsigned short* Pc_[2] = {Pc0, Pc1};
    unsigned short* Qv_[2] = {Qv0, Qv1};

    for (int it = 0; it < LITERS; it++) {
        int rd = it & 1, wr = rd ^ 1;
        int last = (it == LITERS - 1);
        int pen  = (it == LITERS - 2);
        node_fused<<<last ? NVB16 : (NCB16 + NVB16), 256, 0, stream>>>(
            hc, hv, rp_c, rp_v, srcs_c, srcs_v,
            Pv_[rd], Qc_[rd], Pc_[rd], Qv_[rd],
            Pv_[wr], Qc_[wr], Pc_[wr], Qv_[wr],
            Fns_c, bns_c, Fns_v, bns_v,
            Fcat_c, Fcat_v, bg_c, bg_v,
            Fmsg_c, Fmsg_v, bmsg_c, bmsg_v,
            Wf, bf, out, last ? 0 : 1, last ? 1 : 0, pen ? 1 : 0);
    }
}

// Round 13
// 495.528 us; speedup vs baseline: 1.1284x; 1.1284x over previous
//
#include <hip/hip_runtime.h>
#include <hip/hip_bf16.h>
#include <math.h>

#define Hdim 128
#define NCn  8000
#define NVn  16000
#define NE   60000
#define LITERS 10
#define NCB16 500    // c-blocks in node_fused (16 rows)
#define NVB16 1000   // v-blocks in node_fused
#define NCB32 250    // c-blocks in pq phase (32 rows)
#define NVB32 500
#define PREPB 1280   // prep_weights blocks inside prep_init (327680/256)
#define INITB 6000   // init blocks (4 nodes each)
#define HISTB 235    // hist blocks inside prep_init ((NE+255)/256)
#define FILLB 235    // fill blocks inside fill_pq

typedef __attribute__((ext_vector_type(8))) short s8v;   // 8 x bf16 (4 VGPRs)
typedef __attribute__((ext_vector_type(4))) float f4v;   // MFMA acc / float4

// fast transcendentals: v_exp_f32 / v_rcp_f32 based (tolerance is loose, bf16-level)
__device__ __forceinline__ float fexp(float x) { return __expf(x); }
__device__ __forceinline__ float elu_f(float x) { return x > 0.0f ? x : (fexp(x) - 1.0f); }
__device__ __forceinline__ float sigm_f(float x) {
    return __builtin_amdgcn_rcpf(1.0f + fexp(-x));
}
__device__ __forceinline__ float tanh_f(float x) {
    // 1 - 2/(exp(2x)+1); saturates correctly at +/-inf
    return 1.0f - 2.0f * __builtin_amdgcn_rcpf(1.0f + fexp(2.0f * x));
}
__device__ __forceinline__ unsigned short f2b(float x) {
    __hip_bfloat16 h = __float2bfloat16(x); return *(unsigned short*)&h;
}
__device__ __forceinline__ float b2f(unsigned short u) {
    __hip_bfloat16 h; *(unsigned short*)&h = u; return __bfloat162float(h);
}

// ---------------- merged prep: weight fragment cast + node init + edge histogram --------
// blocks [0,PREPB): prep_weights. [PREPB,PREPB+INITB): init (4 nodes/block).
// [PREPB+INITB, +HISTB): histogram of edge targets (cnts pre-zeroed by hipMemsetAsync).
__global__ void prep_init(const float* __restrict__ Wmsg_c, const float* __restrict__ Wmsg_v,
                          const float* __restrict__ Wns_c,  const float* __restrict__ Wns_v,
                          const float* __restrict__ Wg_c, const float* __restrict__ Ug_c,
                          const float* __restrict__ Wg_v, const float* __restrict__ Ug_v,
                          unsigned short* __restrict__ Fmsg_c, unsigned short* __restrict__ Fmsg_v,
                          unsigned short* __restrict__ Fns_c,  unsigned short* __restrict__ Fns_v,
                          unsigned short* __restrict__ Fcat_c, unsigned short* __restrict__ Fcat_v,
                          const float* __restrict__ cf, const float* __restrict__ vf,
                          const float* __restrict__ Wc, const float* __restrict__ bc,
                          const float* __restrict__ Wv, const float* __restrict__ bv,
                          const float* __restrict__ gc, const float* __restrict__ bcl,
                          const float* __restrict__ gv, const float* __restrict__ bvl,
                          float* __restrict__ hc, float* __restrict__ hv,
                          const int* __restrict__ tgt_c, const int* __restrict__ tgt_v,
                          int* __restrict__ cnt_c, int* __restrict__ cnt_v) {
    if (blockIdx.x >= PREPB + INITB) {
        int e = (blockIdx.x - PREPB - INITB) * 256 + threadIdx.x;
        if (e >= NE) return;
        atomicAdd(&cnt_c[tgt_c[e]], 1);
        atomicAdd(&cnt_v[tgt_v[e]], 1);
        return;
    }
    if (blockIdx.x < PREPB) {
        int idx = blockIdx.x * 256 + threadIdx.x;
        const int S1 = 4 * 32768;              // msg_c, msg_v, ns_c, ns_v  (F=8, KT=8, ld=128)
        const int S2 = S1 + 2 * 98304;         // cat_c, cat_v              (F=24, KT=8, ld=384)
        if (idx < S1) {
            int seg = idx >> 15, t = idx & 32767;
            const float* W = (seg == 0) ? Wmsg_c : (seg == 1) ? Wmsg_v : (seg == 2) ? Wns_c : Wns_v;
            unsigned short* outw = (seg == 0) ? Fmsg_c : (seg == 1) ? Fmsg_v : (seg == 2) ? Fns_c : Fns_v;
            int j = t & 7, lane = (t >> 3) & 63, t2 = t >> 9;
            int f = t2 & 7, kt = t2 >> 3;
            int n = f * 16 + (lane & 15), k = kt * 32 + (lane >> 4) * 8 + j;
            outw[t] = f2b(W[(size_t)k * 128 + n]);
        } else if (idx < S2) {
            int q = idx - S1;
            int seg = q / 98304, t = q - seg * 98304;
            const float* Wg = seg ? Wg_v : Wg_c;
            const float* Ug = seg ? Ug_v : Ug_c;
            unsigned short* outw = seg ? Fcat_v : Fcat_c;
            int j = t & 7, lane = (t >> 3) & 63, t2 = t >> 9;
            int f = t2 % 24, kt = t2 / 24;
            int n = f * 16 + (lane & 15), k = kt * 32 + (lane >> 4) * 8 + j;
            outw[t] = f2b((k < 128) ? Ug[(size_t)k * 384 + n] : Wg[(size_t)(k - 128) * 384 + n]);
        }
        return;
    }
    // ---- init: h = LN(0.1*f*W_in + b_in), f32 only ----
    int node = (blockIdx.x - PREPB) * 4 + (threadIdx.x >> 6);
    int lane = threadIdx.x & 63;
    const float *Win, *bin, *g, *bl;
    float f;
    float* outp;
    if (node < NCn) {
        f = cf[node]; Win = Wc; bin = bc; g = gc; bl = bcl;
        outp = hc + (size_t)node * Hdim;
    } else {
        int n2 = node - NCn;
        f = vf[n2]; Win = Wv; bin = bv; g = gv; bl = bvl;
        outp = hv + (size_t)n2 * Hdim;
    }
    f *= 0.1f;
    float x0 = f * Win[lane] + bin[lane];
    float x1 = f * Win[lane + 64] + bin[lane + 64];
    float s = x0 + x1;
    float sq = x0 * x0 + x1 * x1;
    #pragma unroll
    for (int off = 32; off > 0; off >>= 1) {
        s += __shfl_xor(s, off);
        sq += __shfl_xor(sq, off);
    }
    float m = s * (1.0f / 128.0f);
    float v = sq * (1.0f / 128.0f) - m * m;
    float inv = 1.0f / sqrtf(v + 1e-6f);
    outp[lane]      = g[lane]      * (x0 - m) * inv + bl[lane];
    outp[lane + 64] = g[lane + 64] * (x1 - m) * inv + bl[lane + 64];
}

// ---------------- CSR rowptr scan (shfl-based, 2 barriers) ----------------
__launch_bounds__(1024)
__global__ void scan2_kernel(const int* __restrict__ cnt_c, int* __restrict__ rp_c,
                             const int* __restrict__ cnt_v, int* __restrict__ rp_v) {
    const int* cnt = blockIdx.x ? cnt_v : cnt_c;
    int* rowptr = blockIdx.x ? rp_v : rp_c;
    const int n = blockIdx.x ? NVn : NCn;
    __shared__ int wsum[16];
    int t = threadIdx.x;
    int lane = t & 63, wid = t >> 6;
    int chunk = (n + 1023) >> 10;
    int base = t * chunk;
    int s = 0;
    for (int i = 0; i < chunk; i++) { int idx = base + i; if (idx < n) s += cnt[idx]; }
    // wave-level inclusive scan
    int sc = s;
    #pragma unroll
    for (int off = 1; off < 64; off <<= 1) {
        int u = __shfl_up(sc, off);
        if (lane >= off) sc += u;
    }
    if (lane == 63) wsum[wid] = sc;
    __syncthreads();
    if (wid == 0 && lane < 16) {
        int w = wsum[lane];
        int wscan = w;
        #pragma unroll
        for (int off = 1; off < 16; off <<= 1) {
            int u = __shfl_up(wscan, off);
            if (lane >= off) wscan += u;
        }
        wsum[lane] = wscan - w;   // exclusive wave prefix
    }
    __syncthreads();
    int run = wsum[wid] + sc - s;  // exclusive prefix for this thread
    for (int i = 0; i < chunk; i++) {
        int idx = base + i;
        if (idx < n) { rowptr[idx] = run; run += cnt[idx]; }
    }
    if (t == 1023) rowptr[n] = wsum[15] + sc;   // grand total (t=1023 is lane63 of wave15)
}

// ---------------- merged: CSR fill + P/Q init (independent work) ----------------
__launch_bounds__(256)
__global__ void fill_pq(const int* __restrict__ tgt_c, const int* __restrict__ tgt_v,
                        const int* __restrict__ src_c, const int* __restrict__ src_v,
                        const int* __restrict__ rp_c, const int* __restrict__ rp_v,
                        int* __restrict__ fill_c, int* __restrict__ fill_v,
                        int* __restrict__ srcs_c, int* __restrict__ srcs_v,
                        const float* __restrict__ hc, const float* __restrict__ hv,
                        const unsigned short* __restrict__ Fmsg_c, const unsigned short* __restrict__ Fmsg_v,
                        const float* __restrict__ bmsg_c, const float* __restrict__ bmsg_v,
                        unsigned short* __restrict__ Pv_w, unsigned short* __restrict__ Qc_w,
                        unsigned short* __restrict__ Pc_w, unsigned short* __restrict__ Qv_w) {
    if (blockIdx.x < FILLB) {
        int e = blockIdx.x * 256 + threadIdx.x;
        if (e >= NE) return;
        int tc = tgt_c[e];
        srcs_c[rp_c[tc] + atomicAdd(&fill_c[tc], 1)] = src_c[e];
        int tv = tgt_v[e];
        srcs_v[rp_v[tv] + atomicAdd(&fill_v[tv], 1)] = src_v[e];
        return;
    }
    __shared__ unsigned short sA[32 * 136];
    const int bid = blockIdx.x - FILLB;
    const int isV = (bid >= NCB32) ? 1 : 0;
    const int blockM = (isV ? (bid - NCB32) : bid) * 32;
    const float* h = isV ? hv : hc;
    const unsigned short* FP = isV ? Fmsg_c : Fmsg_v;   // P uses the OTHER direction's top half
    const unsigned short* FQ = isV ? Fmsg_v : Fmsg_c;   // Q uses own direction's bottom half
    const float* bq = isV ? bmsg_v : bmsg_c;
    unsigned short* Pw = isV ? Pv_w : Pc_w;
    unsigned short* Qw = isV ? Qv_w : Qc_w;

    const int tid = threadIdx.x;
    const int lane = tid & 63, wave = tid >> 6;
    const int quad = lane >> 4, l16 = lane & 15;
    {
        int rr = tid >> 3, cc = tid & 7;   // 32 rows, 8 threads/row, 16 elems each
        const float* hrow = &h[(size_t)(blockM + rr) * Hdim + cc * 16];
        f4v x0 = *(const f4v*)hrow;
        f4v x1 = *(const f4v*)(hrow + 4);
        f4v x2 = *(const f4v*)(hrow + 8);
        f4v x3 = *(const f4v*)(hrow + 12);
        s8v w0, w1;
        #pragma unroll
        for (int i = 0; i < 4; i++) {
            w0[i] = (short)f2b(x0[i]); w0[i + 4] = (short)f2b(x1[i]);
            w1[i] = (short)f2b(x2[i]); w1[i + 4] = (short)f2b(x3[i]);
        }
        *(s8v*)&sA[rr * 136 + cc * 16]     = w0;
        *(s8v*)&sA[rr * 136 + cc * 16 + 8] = w1;
    }
    __syncthreads();

    f4v accP[2][2], accQ[2][2];   // [mt][u]
    #pragma unroll
    for (int mt = 0; mt < 2; mt++)
        #pragma unroll
        for (int u = 0; u < 2; u++) { accP[mt][u] = (f4v){0.f,0.f,0.f,0.f}; accQ[mt][u] = (f4v){0.f,0.f,0.f,0.f}; }

    #pragma unroll
    for (int kt = 0; kt < 4; kt++) {
        s8v a0 = *(const s8v*)&sA[l16 * 136 + kt * 32 + quad * 8];
        s8v a1 = *(const s8v*)&sA[(16 + l16) * 136 + kt * 32 + quad * 8];
        #pragma unroll
        for (int u = 0; u < 2; u++) {
            int ct = wave * 2 + u;
            s8v bp = *(const s8v*)&FP[((size_t)(kt * 8 + ct) * 64 + lane) * 8];
            s8v bqv = *(const s8v*)&FQ[((size_t)((kt + 4) * 8 + ct) * 64 + lane) * 8];
            accP[0][u] = __builtin_amdgcn_mfma_f32_16x16x32_bf16(a0, bp, accP[0][u], 0, 0, 0);
            accP[1][u] = __builtin_amdgcn_mfma_f32_16x16x32_bf16(a1, bp, accP[1][u], 0, 0, 0);
            accQ[0][u] = __builtin_amdgcn_mfma_f32_16x16x32_bf16(a0, bqv, accQ[0][u], 0, 0, 0);
            accQ[1][u] = __builtin_amdgcn_mfma_f32_16x16x32_bf16(a1, bqv, accQ[1][u], 0, 0, 0);
        }
    }
    #pragma unroll
    for (int u = 0; u < 2; u++) {
        int col = (wave * 2 + u) * 16 + l16;
        float qbias = bq[col];
        #pragma unroll
        for (int mt = 0; mt < 2; mt++)
            #pragma unroll
            for (int reg = 0; reg < 4; reg++) {
                int row = blockM + mt * 16 + quad * 4 + reg;
                Pw[(size_t)row * Hdim + col] = f2b(accP[mt][u][reg]);
                Qw[(size_t)row * Hdim + col] = f2b(accQ[mt][u][reg] + qbias);
            }
    }
}

// ---------------- fused per-iteration node kernel (16-row blocks) ----------------
// NO launch_bounds: the body genuinely needs ~108 VGPRs (8-deep gather batch in flight);
// r12 showed capping it (85) spills to scratch (+52 MB HBM/dispatch, dur 40->51 us).
// stage h(f32->bf16, f32 copy to padded LDS) FUSED with gather (8/4/2/1-deep batched) ->
// bar -> phase A (upd -> sU, fresh region) -> bar -> phase B (gates, split sH1(h@Ug)/
// sH2(upd@Wg)) + epilogue (hold from LDS) -> [last: fused final dot] -> bar -> new-h
// write -> bar -> phase C (next P/Q). Last iteration (vOnly): v-blocks only, no h write.
// skip8: penultimate iteration — c-tiles skip hc/Qc writes, v-tiles skip Pv write.
__global__ void node_fused(float* __restrict__ hc, float* __restrict__ hv,
                           const int* __restrict__ rp_c, const int* __restrict__ rp_v,
                           const int* __restrict__ srcs_c, const int* __restrict__ srcs_v,
                           const unsigned short* __restrict__ Pv_r, const unsigned short* __restrict__ Qc_r,
                           const unsigned short* __restrict__ Pc_r, const unsigned short* __restrict__ Qv_r,
                           unsigned short* __restrict__ Pv_w, unsigned short* __restrict__ Qc_w,
                           unsigned short* __restrict__ Pc_w, unsigned short* __restrict__ Qv_w,
                           const unsigned short* __restrict__ Fns_c, const float* __restrict__ bns_c,
                           const unsigned short* __restrict__ Fns_v, const float* __restrict__ bns_v,
                           const unsigned short* __restrict__ Fcat_c, const unsigned short* __restrict__ Fcat_v,
                           const float* __restrict__ bg_c, const float* __restrict__ bg_v,
                           const unsigned short* __restrict__ Fmsg_c, const unsigned short* __restrict__ Fmsg_v,
                           const float* __restrict__ bmsg_c, const float* __restrict__ bmsg_v,
                           const float* __restrict__ Wf, const float* __restrict__ bf,
                           float* __restrict__ out, int do_pq, int vOnly, int skip8) {
    __shared__ unsigned short sA[16 * 264];   // [16 rows][256 k] stride 264 (8448 B)
    __shared__ unsigned short sU[16 * 136];   // upd rows, bf16 (4352 B)
    __shared__ float sHf[16 * 132];           // f32 copy of old h, stride 132 (8448 B)
    __shared__ float sRed[64];                // final-output reduce
    const int bid = blockIdx.x;
    const int isV = vOnly ? 1 : ((bid >= NCB16) ? 1 : 0);
    const int blockM = (vOnly ? bid : (isV ? (bid - NCB16) : bid)) * 16;
    float* h = isV ? hv : hc;
    const int* rp = isV ? rp_v : rp_c;
    const int* srcs = isV ? srcs_v : srcs_c;
    const unsigned short* Pr = isV ? Pc_r : Pv_r;   // messages into v come from c sources, vice versa
    const unsigned short* Qr = isV ? Qv_r : Qc_r;
    const unsigned short* Fns = isV ? Fns_v : Fns_c;
    const float* bns = isV ? bns_v : bns_c;
    const unsigned short* Fcat = isV ? Fcat_v : Fcat_c;
    const float* bg = isV ? bg_v : bg_c;
    const unsigned short* FP = isV ? Fmsg_c : Fmsg_v;
    const unsigned short* FQ = isV ? Fmsg_v : Fmsg_c;
    const float* bq = isV ? bmsg_v : bmsg_c;
    unsigned short* Pw = isV ? Pv_w : Pc_w;
    unsigned short* Qw = isV ? Qv_w : Qc_w;
    const int wrH = do_pq && !(skip8 && !isV);   // skip hc write on penultimate iter
    const int wrP = !(skip8 && isV);             // skip Pv write on penultimate iter
    const int wrQ = !(skip8 && !isV);            // skip Qc write on penultimate iter

    const int tid = threadIdx.x;
    const int lane = tid & 63, wave = tid >> 6;
    const int quad = lane >> 4, l16 = lane & 15;
    const int r = tid >> 4, ch = tid & 15;    // 16 rows x 16 col-slices of 8
    const int node = blockM + r;

    // ---- fused stage + gather (no barrier in between: gather uses only reg/global) ----
    {
        // independent loads first: Q row-slice, h row-slice, row extent
        s8v q8 = *(const s8v*)&Qr[(size_t)node * Hdim + ch * 8];
        const float* hrow = &h[(size_t)node * Hdim + ch * 8];
        f4v h0 = *(const f4v*)hrow;
        f4v h1 = *(const f4v*)(hrow + 4);
        int j = rp[node];
        const int e0 = rp[node + 1];

        // park h: bf16 into sA, f32 into padded sHf (for GRU hold)
        s8v hw;
        #pragma unroll
        for (int i = 0; i < 4; i++) { hw[i] = (short)f2b(h0[i]); hw[i + 4] = (short)f2b(h1[i]); }
        *(s8v*)&sA[r * 264 + ch * 8] = hw;
        *(f4v*)&sHf[r * 132 + ch * 8]     = h0;
        *(f4v*)&sHf[r * 132 + ch * 8 + 4] = h1;

        float qf[8], acc[8];
        #pragma unroll
        for (int i = 0; i < 8; i++) { qf[i] = b2f((unsigned short)q8[i]); acc[i] = 0.0f; }

        // 8-deep batch (covers most c-rows in one latency epoch)
        for (; j + 8 <= e0; j += 8) {
            s8v p[8];
            #pragma unroll
            for (int b = 0; b < 8; b++)
                p[b] = *(const s8v*)&Pr[(size_t)srcs[j + b] * Hdim + ch * 8];
            #pragma unroll
            for (int b = 0; b < 8; b++)
                #pragma unroll
                for (int i = 0; i < 8; i++) acc[i] += elu_f(b2f((unsigned short)p[b][i]) + qf[i]);
        }
        if (j + 4 <= e0) {
            s8v p[4];
            #pragma unroll
            for (int b = 0; b < 4; b++)
                p[b] = *(const s8v*)&Pr[(size_t)srcs[j + b] * Hdim + ch * 8];
            #pragma unroll
            for (int b = 0; b < 4; b++)
                #pragma unroll
                for (int i = 0; i < 8; i++) acc[i] += elu_f(b2f((unsigned short)p[b][i]) + qf[i]);
            j += 4;
        }
        if (j + 2 <= e0) {
            s8v p0 = *(const s8v*)&Pr[(size_t)srcs[j] * Hdim + ch * 8];
            s8v p1 = *(const s8v*)&Pr[(size_t)srcs[j + 1] * Hdim + ch * 8];
            #pragma unroll
            for (int i = 0; i < 8; i++) acc[i] += elu_f(b2f((unsigned short)p0[i]) + qf[i]);
            #pragma unroll
            for (int i = 0; i < 8; i++) acc[i] += elu_f(b2f((unsigned short)p1[i]) + qf[i]);
            j += 2;
        }
        if (j < e0) {
            s8v p0 = *(const s8v*)&Pr[(size_t)srcs[j] * Hdim + ch * 8];
            #pragma unroll
            for (int i = 0; i < 8; i++) acc[i] += elu_f(b2f((unsigned short)p0[i]) + qf[i]);
        }
        s8v w;
        #pragma unroll
        for (int i = 0; i < 8; i++) w[i] = (short)f2b(acc[i]);
        *(s8v*)&sA[r * 264 + 128 + ch * 8] = w;
    }
    __syncthreads();   // bar1

    // ---- phase A: upd = ELU([h|agg] @ Wns + bns) -> write to fresh sU (no pre-barrier) ----
    f4v accA[2];
    accA[0] = (f4v){0.f,0.f,0.f,0.f};
    accA[1] = (f4v){0.f,0.f,0.f,0.f};
    #pragma unroll
    for (int kt = 0; kt < 8; kt++) {
        s8v a = *(const s8v*)&sA[l16 * 264 + kt * 32 + quad * 8];
        #pragma unroll
        for (int u = 0; u < 2; u++) {
            s8v b = *(const s8v*)&Fns[((size_t)(kt * 8 + wave * 2 + u) * 64 + lane) * 8];
            accA[u] = __builtin_amdgcn_mfma_f32_16x16x32_bf16(a, b, accA[u], 0, 0, 0);
        }
    }
    #pragma unroll
    for (int u = 0; u < 2; u++) {
        int col = (wave * 2 + u) * 16 + l16;
        float bb = bns[col];
        #pragma unroll
        for (int reg = 0; reg < 4; reg++)
            sU[(quad * 4 + reg) * 136 + col] = f2b(elu_f(accA[u][reg] + bb));
    }
    __syncthreads();   // bar2: sU complete

    // ---- phase B: GRU gates; sH1 = h@Ug_h (kt<4), sH2 = upd@Wg_h (kt>=4) ----
    float hnv[2][4];
    #pragma unroll
    for (int u = 0; u < 2; u++) {
        const int j = wave * 2 + u;
        f4v sZ = (f4v){0.f,0.f,0.f,0.f};
        f4v sR = (f4v){0.f,0.f,0.f,0.f};
        f4v sH1 = (f4v){0.f,0.f,0.f,0.f};
        f4v sH2 = (f4v){0.f,0.f,0.f,0.f};
        #pragma unroll
        for (int kt = 0; kt < 8; kt++) {
            s8v a = (kt < 4)
                ? *(const s8v*)&sA[l16 * 264 + kt * 32 + quad * 8]
                : *(const s8v*)&sU[l16 * 136 + (kt - 4) * 32 + quad * 8];
            s8v bz = *(const s8v*)&Fcat[((size_t)(kt * 24 + j) * 64 + lane) * 8];
            s8v br = *(const s8v*)&Fcat[((size_t)(kt * 24 + 8 + j) * 64 + lane) * 8];
            s8v bh = *(const s8v*)&Fcat[((size_t)(kt * 24 + 16 + j) * 64 + lane) * 8];
            sZ = __builtin_amdgcn_mfma_f32_16x16x32_bf16(a, bz, sZ, 0, 0, 0);
            sR = __builtin_amdgcn_mfma_f32_16x16x32_bf16(a, br, sR, 0, 0, 0);
            if (kt < 4)
                sH1 = __builtin_amdgcn_mfma_f32_16x16x32_bf16(a, bh, sH1, 0, 0, 0);
            else
                sH2 = __builtin_amdgcn_mfma_f32_16x16x32_bf16(a, bh, sH2, 0, 0, 0);
        }
        const int t = j * 16 + l16;
        float bz2 = bg[t]       + bg[384 + t];
        float br2 = bg[128 + t] + bg[512 + t];
        float b0h = bg[256 + t];
        float b1h = bg[640 + t];
        #pragma unroll
        for (int reg = 0; reg < 4; reg++) {
            int rloc = quad * 4 + reg;
            float z = sigm_f(sZ[reg] + bz2);
            float rr = sigm_f(sR[reg] + br2);
            float hh = tanh_f((sH2[reg] + b0h) + rr * (sH1[reg] + b1h));
            float hold = sHf[rloc * 132 + t];
            float hn = z * hold + (1.0f - z) * hh;
            if (wrH) h[(size_t)(blockM + rloc) * Hdim + t] = hn;
            hnv[u][reg] = hn;
        }
    }

    if (!do_pq) {
        // ---- last iteration: fused final output out[i] = dot(hv[i], Wf) + bf ----
        float wf0 = Wf[(wave * 2 + 0) * 16 + l16];
        float wf1 = Wf[(wave * 2 + 1) * 16 + l16];
        float part[4];
        #pragma unroll
        for (int reg = 0; reg < 4; reg++)
            part[reg] = hnv[0][reg] * wf0 + hnv[1][reg] * wf1;
        #pragma unroll
        for (int off = 1; off < 16; off <<= 1) {
            #pragma unroll
            for (int reg = 0; reg < 4; reg++)
                part[reg] += __shfl_xor(part[reg], off);
        }
        if (l16 == 0) {
            #pragma unroll
            for (int reg = 0; reg < 4; reg++)
                sRed[wave * 16 + quad * 4 + reg] = part[reg];
        }
        __syncthreads();
        if (tid < 16)
            out[blockM + tid] = sRed[tid] + sRed[16 + tid] + sRed[32 + tid] + sRed[48 + tid] + bf[0];
        return;
    }

    __syncthreads();   // bar3: everyone done reading old h in sA[:,0:128)
    #pragma unroll
    for (int u = 0; u < 2; u++) {
        int col = (wave * 2 + u) * 16 + l16;
        #pragma unroll
        for (int reg = 0; reg < 4; reg++)
            sA[(quad * 4 + reg) * 264 + col] = f2b(hnv[u][reg]);
    }
    __syncthreads();   // bar4

    // ---- phase C: next-iteration P/Q from new h (K=128), bf16 out ----
    f4v accP[2], accQ[2];
    accP[0] = (f4v){0.f,0.f,0.f,0.f}; accP[1] = (f4v){0.f,0.f,0.f,0.f};
    accQ[0] = (f4v){0.f,0.f,0.f,0.f}; accQ[1] = (f4v){0.f,0.f,0.f,0.f};
    #pragma unroll
    for (int kt = 0; kt < 4; kt++) {
        s8v a = *(const s8v*)&sA[l16 * 264 + kt * 32 + quad * 8];
        #pragma unroll
        for (int u = 0; u < 2; u++) {
            int ct = wave * 2 + u;
            s8v bp = *(const s8v*)&FP[((size_t)(kt * 8 + ct) * 64 + lane) * 8];
            s8v bqv = *(const s8v*)&FQ[((size_t)((kt + 4) * 8 + ct) * 64 + lane) * 8];
            accP[u] = __builtin_amdgcn_mfma_f32_16x16x32_bf16(a, bp, accP[u], 0, 0, 0);
            accQ[u] = __builtin_amdgcn_mfma_f32_16x16x32_bf16(a, bqv, accQ[u], 0, 0, 0);
        }
    }
    #pragma unroll
    for (int u = 0; u < 2; u++) {
        int col = (wave * 2 + u) * 16 + l16;
        float qbias = bq[col];
        #pragma unroll
        for (int reg = 0; reg < 4; reg++) {
            int row = blockM + quad * 4 + reg;
            if (wrP) Pw[(size_t)row * Hdim + col] = f2b(accP[u][reg]);
            if (wrQ) Qw[(size_t)row * Hdim + col] = f2b(accQ[u][reg] + qbias);
        }
    }
}

extern "C" void kernel_launch(void* const* d_in, const int* in_sizes, int n_in,
                              void* d_out, int out_size, void* d_ws, size_t ws_size,
                              hipStream_t stream) {
    const float* cf      = (const float*)d_in[0];
    const float* vf      = (const float*)d_in[1];
    const int*   c2v_src = (const int*)d_in[2];
    const int*   c2v_tgt = (const int*)d_in[3];
    const int*   v2c_src = (const int*)d_in[4];
    const int*   v2c_tgt = (const int*)d_in[5];
    const float* Wc_in   = (const float*)d_in[6];
    const float* bc_in   = (const float*)d_in[7];
    const float* Wv_in   = (const float*)d_in[8];
    const float* bv_in   = (const float*)d_in[9];
    const float* gc_ln   = (const float*)d_in[10];
    const float* bc_ln   = (const float*)d_in[11];
    const float* gv_ln   = (const float*)d_in[12];
    const float* bv_ln   = (const float*)d_in[13];
    const float* Wmsg_c  = (const float*)d_in[14];
    const float* bmsg_c  = (const float*)d_in[15];
    const float* Wmsg_v  = (const float*)d_in[16];
    const float* bmsg_v  = (const float*)d_in[17];
    const float* Wns_c   = (const float*)d_in[18];
    const float* bns_c   = (const float*)d_in[19];
    const float* Wns_v   = (const float*)d_in[20];
    const float* bns_v   = (const float*)d_in[21];
    const float* Wg_c    = (const float*)d_in[22];
    const float* Ug_c    = (const float*)d_in[23];
    const float* bg_c    = (const float*)d_in[24];
    const float* Wg_v    = (const float*)d_in[25];
    const float* Ug_v    = (const float*)d_in[26];
    const float* bg_v    = (const float*)d_in[27];
    const float* Wf      = (const float*)d_in[28];
    const float* bf      = (const float*)d_in[29];
    float* out = (float*)d_out;

    // ---- workspace carve (256B-aligned) ----
    char* p = (char*)d_ws;
    #define CARVE(name, type, count) type* name = (type*)p; p += (((size_t)(count) * sizeof(type)) + 255) & ~(size_t)255;
    CARVE(hc,     float, NCn * Hdim)
    CARVE(hv,     float, NVn * Hdim)
    CARVE(Pv0,    unsigned short, NVn * Hdim)
    CARVE(Qc0,    unsigned short, NCn * Hdim)
    CARVE(Pc0,    unsigned short, NCn * Hdim)
    CARVE(Qv0,    unsigned short, NVn * Hdim)
    CARVE(Pv1,    unsigned short, NVn * Hdim)
    CARVE(Qc1,    unsigned short, NCn * Hdim)
    CARVE(Pc1,    unsigned short, NCn * Hdim)
    CARVE(Qv1,    unsigned short, NVn * Hdim)
    CARVE(Fmsg_c, unsigned short, 32768)
    CARVE(Fmsg_v, unsigned short, 32768)
    CARVE(Fns_c,  unsigned short, 32768)
    CARVE(Fns_v,  unsigned short, 32768)
    CARVE(Fcat_c, unsigned short, 98304)
    CARVE(Fcat_v, unsigned short, 98304)
    CARVE(rp_c,  int, NCn + 8)
    CARVE(rp_v,  int, NVn + 8)
    CARVE(srcs_c, int, NE)
    CARVE(srcs_v, int, NE)
    CARVE(cnts,  int, 48000)
    #undef CARVE
    int* cnt_c  = cnts;
    int* cnt_v  = cnts + NCn;
    int* fill_c = cnts + NCn + NVn;
    int* fill_v = cnts + 2 * NCn + NVn;

    // ---- once-per-call prep (memset + 3 dispatches) ----
    hipMemsetAsync(cnts, 0, 48000 * sizeof(int), stream);
    prep_init<<<PREPB + INITB + HISTB, 256, 0, stream>>>(
        Wmsg_c, Wmsg_v, Wns_c, Wns_v, Wg_c, Ug_c, Wg_v, Ug_v,
        Fmsg_c, Fmsg_v, Fns_c, Fns_v, Fcat_c, Fcat_v,
        cf, vf, Wc_in, bc_in, Wv_in, bv_in, gc_ln, bc_ln, gv_ln, bv_ln, hc, hv,
        v2c_tgt, c2v_tgt, cnt_c, cnt_v);
    scan2_kernel<<<2, 1024, 0, stream>>>(cnt_c, rp_c, cnt_v, rp_v);
    fill_pq<<<FILLB + NCB32 + NVB32, 256, 0, stream>>>(
        v2c_tgt, c2v_tgt, v2c_src, c2v_src, rp_c, rp_v, fill_c, fill_v, srcs_c, srcs_v,
        hc, hv, Fmsg_c, Fmsg_v, bmsg_c, bmsg_v, Pv0, Qc0, Pc0, Qv0);

    unsigned short* Pv_[2] = {Pv0, Pv1};
    unsigned short* Qc_[2] = {Qc0, Qc1};
    unsigned short* Pc_[2] = {Pc0, Pc1};
    unsigned short* Qv_[2] = {Qv0, Qv1};

    for (int it = 0; it < LITERS; it++) {
        int rd = it & 1, wr = rd ^ 1;
        int last = (it == LITERS - 1);
        int pen  = (it == LITERS - 2);
        node_fused<<<last ? NVB16 : (NCB16 + NVB16), 256, 0, stream>>>(
            hc, hv, rp_c, rp_v, srcs_c, srcs_v,
            Pv_[rd], Qc_[rd], Pc_[rd], Qv_[rd],
            Pv_[wr], Qc_[wr], Pc_[wr], Qv_[wr],
            Fns_c, bns_c, Fns_v, bns_v,
            Fcat_c, Fcat_v, bg_c, bg_v,
            Fmsg_c, Fmsg_v, bmsg_c, bmsg_v,
            Wf, bf, out, last ? 0 : 1, last ? 1 : 0, pen ? 1 : 0);
    }
}